// Round 17
// baseline (108.116 us; speedup 1.0000x reference)
//
#include <hip/hip_runtime.h>
#include <hip/hip_bf16.h>
#include <math.h>

static constexpr int Bn = 2, Tn = 2048, Dn = 768, Hn = 8, Kn = 64, Vn = 96;

typedef __bf16 bf16x8 __attribute__((ext_vector_type(8)));
typedef __bf16 bf16x4v __attribute__((ext_vector_type(4)));
typedef float f32x4 __attribute__((ext_vector_type(4)));
typedef float f32x16 __attribute__((ext_vector_type(16)));

// fi = #{ i in [1,16] : pr^i - 1 <= a } = floor(log2(a+1) * 16/log2(2049)).
#define F0_SCALE 1.45445233f
#define LOG2E 1.44269504f
#define EXP2F(x) __builtin_amdgcn_exp2f(x)

// Packed fragment-major layouts (per 32-key tile, 64-lane coalesced chunks):
//   kpk[((bh*64 + it)*4 + kt)*512 + lane*8 + i]  = K[bh][it*32 + (lane&31)][kt*16 + (lane>>5)*8 + i]
//   vpk[((bh*64 + it)*6 + c )*512 + lane*8 + i]  = V[bh][it*32 + (c&1)*16 + (lane>>5)*8 + i][(c>>1)*32 + (lane&31)]
//
// HARD-WON SCHEDULING LAW (r7/r10/r13): K loads -> QK -> softmax -> pack -> V loads -> PV,
// all at point of use. ANY load hoisting breaks cross-block L2 lockstep (FETCH 9.5->180MB).
// r15: rwb folded into qhb; rel path uses (rrb - rwb). r16: bias table inside attn preamble.
// r17: GEMM tiles reshaped BMx128 (proj BM=64 -> 896 blocks, out BM=32 -> 768 blocks) to fix
//      grid-starved occupancy (was 448 / 192 blocks on 256 CUs).

// ---------------- fused 4-way transpose + cast (z<4) and x cast (z==4) ----------------
__global__ __launch_bounds__(256) void transpose5_kernel(
    const float* __restrict__ Wq, const float* __restrict__ Wk,
    const float* __restrict__ Wv, const float* __restrict__ Wo,
    const float* __restrict__ x,
    __bf16* __restrict__ WT, __bf16* __restrict__ WoT, __bf16* __restrict__ xb) {
    const int z = blockIdx.z;
    if (z == 4) {
        const int nblk = 24 * 24;
        const int bid = blockIdx.y * 24 + blockIdx.x;
        const int n4 = Bn * Tn * Dn / 4;
        int i = bid * 256 + threadIdx.x;
        const int stride = nblk * 256;
        for (; i < n4; i += stride) {
            const float4 v = ((const float4*)x)[i];
            bf16x4v o; o[0] = (__bf16)v.x; o[1] = (__bf16)v.y; o[2] = (__bf16)v.z; o[3] = (__bf16)v.w;
            ((bf16x4v*)xb)[i] = o;
        }
        return;
    }
    __shared__ float tile[32][33];
    const float* W; __bf16* O; int Nd;
    if (z == 0)      { W = Wq; O = WT;                        Nd = 512; }
    else if (z == 1) { W = Wk; O = WT + (size_t)512 * 768;    Nd = 512; }
    else if (z == 2) { W = Wv; O = WT + (size_t)1024 * 768;   Nd = 768; }
    else             { W = Wo; O = WoT;                       Nd = 768; }
    const int n0 = blockIdx.x * 32, k0 = blockIdx.y * 32;
    if (n0 >= Nd) return;
    const int tx = threadIdx.x & 31, ty8 = threadIdx.x >> 5;
    for (int r = ty8; r < 32; r += 8)
        tile[r][tx] = W[(size_t)(k0 + r) * Nd + n0 + tx];
    __syncthreads();
    for (int r = ty8; r < 32; r += 8)
        O[(size_t)(n0 + r) * 768 + k0 + tx] = (__bf16)tile[tx][r];
}

// ---------------- bf16 MFMA GEMM: C[BM x 128 / block] = A[M][Kd] @ BT[N][Kd]^T ----------------
// 4 waves; wave w owns cols [w*32, w*32+32). mode 0: proj scatter (bo=rwb fold);
// mode 1: out (+bias bo, f32).
template <int BM, int MODE>
__global__ __launch_bounds__(256) void gemm_kernel(
    const __bf16* __restrict__ A, const __bf16* __restrict__ BT, int Kd,
    __bf16* __restrict__ qhb, __bf16* __restrict__ kpk, __bf16* __restrict__ vpk,
    float* __restrict__ outp, const float* __restrict__ bo) {
    __shared__ __attribute__((aligned(16))) __bf16 smemA[2][BM * 32];
    __shared__ __attribute__((aligned(16))) __bf16 smemB[2][128 * 32];
    const int tid = threadIdx.x;
    const int w = tid >> 6, lane = tid & 63, g = lane >> 4, r16 = lane & 15;
    const int rowBase = blockIdx.y * BM, colBase = blockIdx.x * 128;
    const int NK = Kd >> 5;
    constexpr int MI = BM / 16;

    // staging: 16B chunks; A has BM*4 chunks, B has 512 chunks (2/thread)
    const int srow = tid >> 2, part = tid & 3;
    const bool aact = (BM == 64) || (tid < 128);
    const size_t Aoff = (size_t)(rowBase + (srow & (BM - 1))) * Kd + part * 8;
    const size_t Boff0 = (size_t)(colBase + srow) * Kd + part * 8;
    const size_t Boff1 = (size_t)(colBase + 64 + srow) * Kd + part * 8;
    const int woffA = ((srow & (BM - 1)) * 64 + part * 16) ^ (((srow & (BM - 1)) & 7) << 4);
    const int woffB0 = (srow * 64 + part * 16) ^ ((srow & 7) << 4);
    const int woffB1 = ((64 + srow) * 64 + part * 16) ^ ((srow & 7) << 4);

    int aoff[MI], boff[2];
#pragma unroll
    for (int i = 0; i < MI; ++i) {
        const int rowA = i * 16 + r16;
        aoff[i] = (rowA * 64 + g * 16) ^ ((rowA & 7) << 4);
    }
#pragma unroll
    for (int j = 0; j < 2; ++j) {
        const int rowB = w * 32 + j * 16 + r16;
        boff[j] = (rowB * 64 + g * 16) ^ ((rowB & 7) << 4);
    }

    f32x4 acc[MI][2];
#pragma unroll
    for (int i = 0; i < MI; ++i)
#pragma unroll
        for (int j = 0; j < 2; ++j) acc[i][j] = (f32x4){0.f, 0.f, 0.f, 0.f};

    uint4 ar = aact ? *(const uint4*)(A + Aoff) : uint4{0, 0, 0, 0};
    uint4 br0 = *(const uint4*)(BT + Boff0);
    uint4 br1 = *(const uint4*)(BT + Boff1);
    {
        char* Ab = (char*)&smemA[0][0];
        char* Bb = (char*)&smemB[0][0];
        if (aact) *(uint4*)(Ab + woffA) = ar;
        *(uint4*)(Bb + woffB0) = br0;
        *(uint4*)(Bb + woffB1) = br1;
    }
    __syncthreads();
    int cur = 0;
    for (int kt = 0; kt < NK; ++kt) {
        if (kt + 1 < NK) {
            const size_t kb = (size_t)(kt + 1) * 32;
            if (aact) ar = *(const uint4*)(A + Aoff + kb);
            br0 = *(const uint4*)(BT + Boff0 + kb);
            br1 = *(const uint4*)(BT + Boff1 + kb);
        }
        char* Ab = (char*)&smemA[cur][0];
        char* Bb = (char*)&smemB[cur][0];
        bf16x8 af[MI], bfr[2];
#pragma unroll
        for (int i = 0; i < MI; ++i) af[i] = *(const bf16x8*)(Ab + aoff[i]);
#pragma unroll
        for (int j = 0; j < 2; ++j) bfr[j] = *(const bf16x8*)(Bb + boff[j]);
#pragma unroll
        for (int i = 0; i < MI; ++i)
#pragma unroll
            for (int j = 0; j < 2; ++j)
                acc[i][j] = __builtin_amdgcn_mfma_f32_16x16x32_bf16(af[i], bfr[j], acc[i][j], 0, 0, 0);
        if (kt + 1 < NK) {
            char* An = (char*)&smemA[cur ^ 1][0];
            char* Bpn = (char*)&smemB[cur ^ 1][0];
            if (aact) *(uint4*)(An + woffA) = ar;
            *(uint4*)(Bpn + woffB0) = br0;
            *(uint4*)(Bpn + woffB1) = br1;
        }
        __syncthreads();
        cur ^= 1;
    }
    if (MODE == 0) {
#pragma unroll
        for (int i = 0; i < MI; ++i)
#pragma unroll
            for (int j = 0; j < 2; ++j)
#pragma unroll
                for (int reg = 0; reg < 4; ++reg) {
                    const int row = rowBase + i * 16 + 4 * g + reg;
                    const int col = colBase + w * 32 + j * 16 + r16;
                    const float v = acc[i][j][reg];
                    const int b = row >> 11, t = row & (Tn - 1);
                    const int it = t >> 5;
                    if (col < 512) {
                        // content-bias fold: qhb = q/8 + r_w_bias  (bo == rwb here)
                        qhb[(((size_t)b * Hn + (col >> 6)) * Tn + t) * Kn + (col & 63)] =
                            (__bf16)(v * 0.125f + bo[col]);
                    } else if (col < 1024) {
                        const int c2 = col - 512;
                        const int bh = b * Hn + (c2 >> 6), kk = c2 & 63;
                        const int ktc = kk >> 4, hi = (kk >> 3) & 1, ii = kk & 7;
                        kpk[(size_t)(((bh * 64 + it) * 4 + ktc) * 64 + hi * 32 + (t & 31)) * 8 + ii] =
                            (__bf16)(v * LOG2E);
                    } else {
                        const int c3 = col - 1024;
                        const int bh = b * Hn + c3 / 96, vv = c3 % 96;
                        const int c = (vv >> 5) * 2 + ((t >> 4) & 1), hi = (t >> 3) & 1, ii = t & 7;
                        vpk[(size_t)(((bh * 64 + it) * 6 + c) * 64 + hi * 32 + (vv & 31)) * 8 + ii] =
                            (__bf16)v;
                    }
                }
    } else {
#pragma unroll
        for (int i = 0; i < MI; ++i)
#pragma unroll
            for (int j = 0; j < 2; ++j)
#pragma unroll
                for (int reg = 0; reg < 4; ++reg) {
                    const int row = rowBase + i * 16 + 4 * g + reg;
                    const int col = colBase + w * 32 + j * 16 + r16;
                    outp[(size_t)row * Dn + col] = acc[i][j][reg] + bo[col];
                }
    }
}

// ---------------- MFMA flash attention: r9 loop + in-kernel bias table (r16) ----------------
__global__ __launch_bounds__(256, 4) void attn_kernel(
    const __bf16* __restrict__ qhb, const __bf16* __restrict__ kpk,
    const __bf16* __restrict__ vpk, const float* __restrict__ Wrk,
    const float* __restrict__ rwb, const float* __restrict__ rrb,
    __bf16* __restrict__ P) {
    __shared__ float SsL[32][35];
    __shared__ unsigned char dtab[4096];
    __shared__ float mlbuf[4][32][2];
    __shared__ float linv[32];
    __shared__ float obufA[32][97];
    __shared__ float obufB[32][97];
    const int tid = threadIdx.x;
    const int w = tid >> 6, lane = tid & 63;
    const int q = lane & 31, hi = lane >> 5;
    const int n = blockIdx.x;
    const int xcd = n & 7, slot = n >> 3;
    const int bh = xcd + 8 * (slot >> 6);
    const int t0 = (slot & 63) * 32;
    const int b = bh >> 3, h = bh & 7;

    const __bf16* qrow = qhb + ((size_t)bh * Tn + t0 + q) * Kn + hi * 8;
    bf16x8 qf[4];
#pragma unroll
    for (int kt = 0; kt < 4; ++kt) qf[kt] = *(const bf16x8*)(qrow + kt * 16);

    for (int idx = tid; idx < 4095; idx += 256) {
        const int d = idx - 2047;
        const int a = d < 0 ? -d : d;
        const int fi = (int)(__log2f((float)(a + 1)) * F0_SCALE);
        const int col = d > 0 ? fi : (d < 0 ? 17 + fi : 34);
        dtab[idx] = (unsigned char)(col * 4);
    }

    float* wlds = &obufB[0][0];
    for (int idx = tid; idx < 512; idx += 256) {
        const int i = idx >> 4, jj = (idx & 15) * 4;
        *(float4*)&wlds[i * 64 + jj] = *(const float4*)&Wrk[(size_t)i * (Hn * Kn) + h * Kn + jj];
    }
    __syncthreads();

    {
        float val[32];
#pragma unroll
        for (int kt = 0; kt < 4; ++kt) {
            const int kb = kt * 16 + hi * 8;
            const float4 ra = *(const float4*)&rrb[h * Kn + kb];
            const float4 rb = *(const float4*)&rrb[h * Kn + kb + 4];
            const float4 wa = *(const float4*)&rwb[h * Kn + kb];
            const float4 wb = *(const float4*)&rwb[h * Kn + kb + 4];
            val[kt * 8 + 0] = (float)qf[kt][0] + (ra.x - wa.x);
            val[kt * 8 + 1] = (float)qf[kt][1] + (ra.y - wa.y);
            val[kt * 8 + 2] = (float)qf[kt][2] + (ra.z - wa.z);
            val[kt * 8 + 3] = (float)qf[kt][3] + (ra.w - wa.w);
            val[kt * 8 + 4] = (float)qf[kt][4] + (rb.x - wb.x);
            val[kt * 8 + 5] = (float)qf[kt][5] + (rb.y - wb.y);
            val[kt * 8 + 6] = (float)qf[kt][6] + (rb.z - wb.z);
            val[kt * 8 + 7] = (float)qf[kt][7] + (rb.w - wb.w);
        }
#pragma unroll
        for (int il = 0; il < 8; ++il) {
            const int i = w * 8 + il;
            float partial = 0.f;
#pragma unroll
            for (int kt = 0; kt < 4; ++kt) {
                const int kb = kt * 16 + hi * 8;
                const float4 w0 = *(const float4*)&wlds[i * 64 + kb];
                const float4 w1 = *(const float4*)&wlds[i * 64 + kb + 4];
                partial += val[kt * 8 + 0] * w0.x + val[kt * 8 + 1] * w0.y +
                           val[kt * 8 + 2] * w0.z + val[kt * 8 + 3] * w0.w +
                           val[kt * 8 + 4] * w1.x + val[kt * 8 + 5] * w1.y +
                           val[kt * 8 + 6] * w1.z + val[kt * 8 + 7] * w1.w;
            }
            partial += __shfl_xor(partial, 32);
            if (hi == 0) obufA[q][i] = partial;
        }
    }
    __syncthreads();
    if (tid < 32) {
        const int row = tid;
        float* dst = SsL[row];
        float s1 = 0.f, s2 = 0.f;
        dst[16] = 0.f; dst[33] = 0.f;
        for (int i = 15; i >= 0; --i) {
            s1 += obufA[row][i]; s2 += obufA[row][16 + i];
            dst[i] = (s1 + s2) * LOG2E;
            dst[17 + i] = (s1 - s2) * LOG2E;
        }
        dst[34] = s1 * LOG2E;
    }

    f32x16 acc0 = {0.f}, acc1 = {0.f}, acc2 = {0.f};
    float m = -3.0e38f, l = 0.f;

    const size_t kp0 = (size_t)(bh * 64) * 4 * 512 + lane * 8;
    const size_t vp0 = (size_t)(bh * 64) * 6 * 512 + lane * 8;
    const int sBeg = w * (Tn / 4);
    const char* sslrow = (const char*)(&SsL[q][0]);

    __syncthreads();

    for (int itile = 0; itile < Tn / 4 / 32; ++itile) {
        const int s0 = sBeg + itile * 32;
        const int tIdx = s0 >> 5;
        const __bf16* kr = kpk + kp0 + (size_t)tIdx * (4 * 512);
        f32x16 st = {0.f};
#pragma unroll
        for (int kt = 0; kt < 4; ++kt) {
            const bf16x8 kf = *(const bf16x8*)(kr + kt * 512);
            st = __builtin_amdgcn_mfma_f32_32x32x16_bf16(kf, qf[kt], st, 0, 0, 0);
        }
        const unsigned char* dp = dtab + (s0 - t0 - q + 2047);
        float p[16];
        float mt = -3.0e38f;
#pragma unroll
        for (int r = 0; r < 16; ++r) {
            const int kr2 = (r & 3) + 8 * (r >> 2) + 4 * hi;
            const int off = dp[kr2];
            const float bias = *(const float*)(sslrow + off);
            p[r] = st[r] + bias;
            mt = fmaxf(mt, p[r]);
        }
        if (!__all(mt - m <= 8.0f)) {
            mt = fmaxf(mt, __shfl_xor(mt, 32));
            const float mn = fmaxf(m, mt);
            const float sc = EXP2F(m - mn);
            m = mn;
            l *= sc;
            acc0 *= sc; acc1 *= sc; acc2 *= sc;
        }
        float ssum = 0.f;
#pragma unroll
        for (int r = 0; r < 16; ++r) { p[r] = EXP2F(p[r] - m); ssum += p[r]; }
        ssum += __shfl_xor(ssum, 32);
        l += ssum;
        unsigned int c[8];
#pragma unroll
        for (int i = 0; i < 8; ++i) {
            union { __bf16 hh[2]; unsigned int u; } uu;
            uu.hh[0] = (__bf16)p[2 * i]; uu.hh[1] = (__bf16)p[2 * i + 1];
            c[i] = uu.u;
        }
        union { unsigned int u[4]; bf16x8 v; } B0, B1;
#if __has_builtin(__builtin_amdgcn_permlane32_swap)
        {
            auto r0 = __builtin_amdgcn_permlane32_swap((int)c[0], (int)c[2], false, false);
            auto r1 = __builtin_amdgcn_permlane32_swap((int)c[1], (int)c[3], false, false);
            auto r2 = __builtin_amdgcn_permlane32_swap((int)c[4], (int)c[6], false, false);
            auto r3 = __builtin_amdgcn_permlane32_swap((int)c[5], (int)c[7], false, false);
            B0.u[0] = (unsigned int)r0[0]; B0.u[2] = (unsigned int)r0[1];
            B0.u[1] = (unsigned int)r1[0]; B0.u[3] = (unsigned int)r1[1];
            B1.u[0] = (unsigned int)r2[0]; B1.u[2] = (unsigned int)r2[1];
            B1.u[1] = (unsigned int)r3[0]; B1.u[3] = (unsigned int)r3[1];
        }
#else
        {
            unsigned int x[8];
#pragma unroll
            for (int i = 0; i < 8; ++i) x[i] = __shfl_xor(c[i], 32);
            B0.u[0] = hi ? x[2] : c[0]; B0.u[1] = hi ? x[3] : c[1];
            B0.u[2] = hi ? c[2] : x[0]; B0.u[3] = hi ? c[3] : x[1];
            B1.u[0] = hi ? x[6] : c[4]; B1.u[1] = hi ? x[7] : c[5];
            B1.u[2] = hi ? c[6] : x[4]; B1.u[3] = hi ? c[7] : x[5];
        }
#endif
        const __bf16* vr = vpk + vp0 + (size_t)tIdx * (6 * 512);
        acc0 = __builtin_amdgcn_mfma_f32_32x32x16_bf16(*(const bf16x8*)(vr + 0 * 512), B0.v, acc0, 0, 0, 0);
        acc0 = __builtin_amdgcn_mfma_f32_32x32x16_bf16(*(const bf16x8*)(vr + 1 * 512), B1.v, acc0, 0, 0, 0);
        acc1 = __builtin_amdgcn_mfma_f32_32x32x16_bf16(*(const bf16x8*)(vr + 2 * 512), B0.v, acc1, 0, 0, 0);
        acc1 = __builtin_amdgcn_mfma_f32_32x32x16_bf16(*(const bf16x8*)(vr + 3 * 512), B1.v, acc1, 0, 0, 0);
        acc2 = __builtin_amdgcn_mfma_f32_32x32x16_bf16(*(const bf16x8*)(vr + 4 * 512), B0.v, acc2, 0, 0, 0);
        acc2 = __builtin_amdgcn_mfma_f32_32x32x16_bf16(*(const bf16x8*)(vr + 5 * 512), B1.v, acc2, 0, 0, 0);
    }

    if (lane < 32) { mlbuf[w][q][0] = m; mlbuf[w][q][1] = l; }
    __syncthreads();
    const float mstar = fmaxf(fmaxf(mlbuf[0][q][0], mlbuf[1][q][0]),
                              fmaxf(mlbuf[2][q][0], mlbuf[3][q][0]));
    const float wme = EXP2F(m - mstar);
    if (w == 0 && lane < 32) {
        float ls = 0.f;
#pragma unroll
        for (int ww = 0; ww < 4; ++ww)
            ls += mlbuf[ww][q][1] * EXP2F(mlbuf[ww][q][0] - mstar);
        linv[q] = 1.f / ls;
    }
    float (*bufp)[97] = (w & 1) ? obufB : obufA;
    if (w < 2) {
#pragma unroll
        for (int r = 0; r < 16; ++r) {
            const int vr2 = (r & 3) + 8 * (r >> 2) + 4 * hi;
            bufp[q][vr2] = acc0[r] * wme;
            bufp[q][32 + vr2] = acc1[r] * wme;
            bufp[q][64 + vr2] = acc2[r] * wme;
        }
    }
    __syncthreads();
    if (w >= 2) {
#pragma unroll
        for (int r = 0; r < 16; ++r) {
            const int vr2 = (r & 3) + 8 * (r >> 2) + 4 * hi;
            bufp[q][vr2] += acc0[r] * wme;
            bufp[q][32 + vr2] += acc1[r] * wme;
            bufp[q][64 + vr2] += acc2[r] * wme;
        }
    }
    __syncthreads();
    const int qo = tid >> 3, v0 = (tid & 7) * 12;
    const float li = linv[qo];
    __bf16* prow = P + ((size_t)b * Tn + t0 + qo) * Dn + h * Vn + v0;
#pragma unroll
    for (int j = 0; j < 12; j += 2) {
        const float u0 = (obufA[qo][v0 + j] + obufB[qo][v0 + j]) * li;
        const float u1 = (obufA[qo][v0 + j + 1] + obufB[qo][v0 + j + 1]) * li;
        union { __bf16 hh[2]; unsigned int u; } pk;
        pk.hh[0] = (__bf16)u0; pk.hh[1] = (__bf16)u1;
        *(unsigned int*)(prow + j) = pk.u;
    }
}

extern "C" void kernel_launch(void* const* d_in, const int* in_sizes, int n_in,
                              void* d_out, int out_size, void* d_ws, size_t ws_size,
                              hipStream_t stream) {
    (void)in_sizes; (void)n_in; (void)out_size; (void)ws_size;
    const float* x   = (const float*)d_in[0];
    const float* Wq  = (const float*)d_in[1];
    const float* Wk  = (const float*)d_in[2];
    const float* Wv  = (const float*)d_in[3];
    const float* Wrk = (const float*)d_in[4];
    const float* rwb = (const float*)d_in[5];
    const float* rrb = (const float*)d_in[6];
    const float* Wo  = (const float*)d_in[7];
    const float* bo  = (const float*)d_in[8];
    float* out = (float*)d_out;

    char* p = (char*)d_ws;
    auto alloc = [&](size_t bytes) { char* r = p; p += (bytes + 255) & ~(size_t)255; return r; };
    __bf16* qhb  = (__bf16*)alloc((size_t)Bn * Hn * Tn * Kn * 2);
    __bf16* kpk  = (__bf16*)alloc((size_t)Bn * Hn * 64 * 4 * 512 * 2);
    __bf16* vpk  = (__bf16*)alloc((size_t)Bn * Hn * 64 * 6 * 512 * 2);
    __bf16* Pmb  = (__bf16*)alloc((size_t)Bn * Tn * Dn * 2);
    __bf16* Xb   = (__bf16*)alloc((size_t)Bn * Tn * Dn * 2);
    __bf16* WT   = (__bf16*)alloc((size_t)1792 * 768 * 2);
    __bf16* WoT  = (__bf16*)alloc((size_t)768 * 768 * 2);

    transpose5_kernel<<<dim3(24, 24, 5), 256, 0, stream>>>(Wq, Wk, Wv, Wo, x, WT, WoT, Xb);
    gemm_kernel<64, 0><<<dim3(14, 64), 256, 0, stream>>>(Xb, WT, 768, qhb, kpk, vpk, nullptr, rwb);
    attn_kernel<<<dim3(1024), 256, 0, stream>>>(qhb, kpk, vpk, Wrk, rwb, rrb, Pmb);
    gemm_kernel<32, 1><<<dim3(6, 128), 256, 0, stream>>>(Pmb, WoT, 768, nullptr, nullptr, nullptr, out, bo);
}

// Round 18
// 102.783 us; speedup vs baseline: 1.0519x; 1.0519x over previous
//
#include <hip/hip_runtime.h>
#include <hip/hip_bf16.h>
#include <math.h>

static constexpr int Bn = 2, Tn = 2048, Dn = 768, Hn = 8, Kn = 64, Vn = 96;

typedef __bf16 bf16x8 __attribute__((ext_vector_type(8)));
typedef __bf16 bf16x4v __attribute__((ext_vector_type(4)));
typedef float f32x4 __attribute__((ext_vector_type(4)));
typedef float f32x16 __attribute__((ext_vector_type(16)));

// fi = #{ i in [1,16] : pr^i - 1 <= a } = floor(log2(a+1) * 16/log2(2049)).
#define F0_SCALE 1.45445233f
#define LOG2E 1.44269504f
#define EXP2F(x) __builtin_amdgcn_exp2f(x)

// Packed fragment-major layouts (per 32-key tile, 64-lane coalesced chunks):
//   kpk[((bh*64 + it)*4 + kt)*512 + lane*8 + i]  = K[bh][it*32 + (lane&31)][kt*16 + (lane>>5)*8 + i]
//   vpk[((bh*64 + it)*6 + c )*512 + lane*8 + i]  = V[bh][it*32 + (c&1)*16 + (lane>>5)*8 + i][(c>>1)*32 + (lane&31)]
//
// HARD-WON LAWS:
//  - r7/r10/r13: attn loads strictly at point of use (K -> QK -> softmax -> pack -> V -> PV);
//    any hoisting breaks cross-block L2 lockstep (FETCH 9.5 -> 18-180MB, 1.3-2x slower).
//  - r17: GEMM 128x128 tile is optimal at these shapes; smaller BM doubles B staging traffic
//    and halves the MFMA chain per barrier -> net loss despite higher occupancy.
// r15: rwb folded into qhb; rel path uses (rrb - rwb). r16: bias table inside attn preamble.

// ---------------- fused 4-way transpose + cast (z<4) and x cast (z==4) ----------------
__global__ __launch_bounds__(256) void transpose5_kernel(
    const float* __restrict__ Wq, const float* __restrict__ Wk,
    const float* __restrict__ Wv, const float* __restrict__ Wo,
    const float* __restrict__ x,
    __bf16* __restrict__ WT, __bf16* __restrict__ WoT, __bf16* __restrict__ xb) {
    const int z = blockIdx.z;
    if (z == 4) {
        const int nblk = 24 * 24;
        const int bid = blockIdx.y * 24 + blockIdx.x;
        const int n4 = Bn * Tn * Dn / 4;
        int i = bid * 256 + threadIdx.x;
        const int stride = nblk * 256;
        for (; i < n4; i += stride) {
            const float4 v = ((const float4*)x)[i];
            bf16x4v o; o[0] = (__bf16)v.x; o[1] = (__bf16)v.y; o[2] = (__bf16)v.z; o[3] = (__bf16)v.w;
            ((bf16x4v*)xb)[i] = o;
        }
        return;
    }
    __shared__ float tile[32][33];
    const float* W; __bf16* O; int Nd;
    if (z == 0)      { W = Wq; O = WT;                        Nd = 512; }
    else if (z == 1) { W = Wk; O = WT + (size_t)512 * 768;    Nd = 512; }
    else if (z == 2) { W = Wv; O = WT + (size_t)1024 * 768;   Nd = 768; }
    else             { W = Wo; O = WoT;                       Nd = 768; }
    const int n0 = blockIdx.x * 32, k0 = blockIdx.y * 32;
    if (n0 >= Nd) return;
    const int tx = threadIdx.x & 31, ty8 = threadIdx.x >> 5;
    for (int r = ty8; r < 32; r += 8)
        tile[r][tx] = W[(size_t)(k0 + r) * Nd + n0 + tx];
    __syncthreads();
    for (int r = ty8; r < 32; r += 8)
        O[(size_t)(n0 + r) * 768 + k0 + tx] = (__bf16)tile[tx][r];
}

// ---------------- bf16 MFMA GEMM: C[128x128/block] = A[M][Kd] @ BT[N][Kd]^T ----------------
// mode 0: proj epilogue (scatter; bo = r_w_bias, folded into qhb)
// mode 1: out epilogue (+bias bo, f32)
__global__ __launch_bounds__(256) void gemm_kernel(
    const __bf16* __restrict__ A, const __bf16* __restrict__ BT, int Kd, int mode,
    __bf16* __restrict__ qhb, __bf16* __restrict__ kpk, __bf16* __restrict__ vpk,
    float* __restrict__ outp, const float* __restrict__ bo) {
    __shared__ __attribute__((aligned(16))) __bf16 smem[2][2][128 * 32];
    const int tid = threadIdx.x;
    const int w = tid >> 6, lane = tid & 63, g = lane >> 4, r16 = lane & 15;
    const int wr = w >> 1, wc = w & 1;
    const int rowBase = blockIdx.y * 128, colBase = blockIdx.x * 128;
    const int NK = Kd >> 5;

    const int srow0 = tid >> 2, part = tid & 3;
    const size_t Aoff0 = (size_t)(rowBase + srow0) * Kd + part * 8;
    const size_t Aoff1 = (size_t)(rowBase + 64 + srow0) * Kd + part * 8;
    const size_t Boff0 = (size_t)(colBase + srow0) * Kd + part * 8;
    const size_t Boff1 = (size_t)(colBase + 64 + srow0) * Kd + part * 8;
    const int sw = (srow0 & 7) << 4;
    const int woff0 = (srow0 * 64 + part * 16) ^ sw;
    const int woff1 = ((64 + srow0) * 64 + part * 16) ^ sw;

    int aoff[4], boff[4];
#pragma unroll
    for (int i = 0; i < 4; ++i) {
        const int rowA = wr * 64 + i * 16 + r16;
        aoff[i] = (rowA * 64 + g * 16) ^ ((rowA & 7) << 4);
        const int rowB = wc * 64 + i * 16 + r16;
        boff[i] = (rowB * 64 + g * 16) ^ ((rowB & 7) << 4);
    }

    f32x4 acc[4][4];
#pragma unroll
    for (int i = 0; i < 4; ++i)
#pragma unroll
        for (int j = 0; j < 4; ++j) acc[i][j] = (f32x4){0.f, 0.f, 0.f, 0.f};

    uint4 ar0 = *(const uint4*)(A + Aoff0);
    uint4 ar1 = *(const uint4*)(A + Aoff1);
    uint4 br0 = *(const uint4*)(BT + Boff0);
    uint4 br1 = *(const uint4*)(BT + Boff1);
    {
        char* Ab = (char*)&smem[0][0][0];
        char* Bb = (char*)&smem[0][1][0];
        *(uint4*)(Ab + woff0) = ar0; *(uint4*)(Ab + woff1) = ar1;
        *(uint4*)(Bb + woff0) = br0; *(uint4*)(Bb + woff1) = br1;
    }
    __syncthreads();
    int cur = 0;
    for (int kt = 0; kt < NK; ++kt) {
        if (kt + 1 < NK) {
            const size_t kb = (size_t)(kt + 1) * 32;
            ar0 = *(const uint4*)(A + Aoff0 + kb);
            ar1 = *(const uint4*)(A + Aoff1 + kb);
            br0 = *(const uint4*)(BT + Boff0 + kb);
            br1 = *(const uint4*)(BT + Boff1 + kb);
        }
        char* Ab = (char*)&smem[cur][0][0];
        char* Bb = (char*)&smem[cur][1][0];
        bf16x8 af[4], bfr[4];
#pragma unroll
        for (int i = 0; i < 4; ++i) af[i] = *(const bf16x8*)(Ab + aoff[i]);
#pragma unroll
        for (int j = 0; j < 4; ++j) bfr[j] = *(const bf16x8*)(Bb + boff[j]);
#pragma unroll
        for (int i = 0; i < 4; ++i)
#pragma unroll
            for (int j = 0; j < 4; ++j)
                acc[i][j] = __builtin_amdgcn_mfma_f32_16x16x32_bf16(af[i], bfr[j], acc[i][j], 0, 0, 0);
        if (kt + 1 < NK) {
            char* An = (char*)&smem[cur ^ 1][0][0];
            char* Bpn = (char*)&smem[cur ^ 1][1][0];
            *(uint4*)(An + woff0) = ar0; *(uint4*)(An + woff1) = ar1;
            *(uint4*)(Bpn + woff0) = br0; *(uint4*)(Bpn + woff1) = br1;
        }
        __syncthreads();
        cur ^= 1;
    }
    if (mode == 0) {
#pragma unroll
        for (int i = 0; i < 4; ++i)
#pragma unroll
            for (int j = 0; j < 4; ++j)
#pragma unroll
                for (int reg = 0; reg < 4; ++reg) {
                    const int row = rowBase + wr * 64 + i * 16 + 4 * g + reg;
                    const int col = colBase + wc * 64 + j * 16 + r16;
                    const float v = acc[i][j][reg];
                    const int b = row >> 11, t = row & (Tn - 1);
                    const int it = t >> 5;
                    if (col < 512) {
                        // content-bias fold: qhb = q/8 + r_w_bias  (bo == rwb here)
                        qhb[(((size_t)b * Hn + (col >> 6)) * Tn + t) * Kn + (col & 63)] =
                            (__bf16)(v * 0.125f + bo[col]);
                    } else if (col < 1024) {
                        const int c2 = col - 512;
                        const int bh = b * Hn + (c2 >> 6), kk = c2 & 63;
                        const int ktc = kk >> 4, hi = (kk >> 3) & 1, ii = kk & 7;
                        // k pre-scaled by log2(e): logits in base-2 units
                        kpk[(size_t)(((bh * 64 + it) * 4 + ktc) * 64 + hi * 32 + (t & 31)) * 8 + ii] =
                            (__bf16)(v * LOG2E);
                    } else {
                        const int c3 = col - 1024;
                        const int bh = b * Hn + c3 / 96, vv = c3 % 96;
                        const int c = (vv >> 5) * 2 + ((t >> 4) & 1), hi = (t >> 3) & 1, ii = t & 7;
                        vpk[(size_t)(((bh * 64 + it) * 6 + c) * 64 + hi * 32 + (vv & 31)) * 8 + ii] =
                            (__bf16)v;
                    }
                }
    } else {
#pragma unroll
        for (int i = 0; i < 4; ++i)
#pragma unroll
            for (int j = 0; j < 4; ++j)
#pragma unroll
                for (int reg = 0; reg < 4; ++reg) {
                    const int row = rowBase + wr * 64 + i * 16 + 4 * g + reg;
                    const int col = colBase + wc * 64 + j * 16 + r16;
                    outp[(size_t)row * Dn + col] = acc[i][j][reg] + bo[col];
                }
    }
}

// ---------------- MFMA flash attention: r9 loop + in-kernel bias table (r16) ----------------
// 1024 blocks, XCD-swizzled. Block: 32 q-rows, 4 waves; wave w owns 512 keys.
// Preamble computes SsL from qf + Wrk (obufB reused as Wrk LDS, obufA as us scratch).
__global__ __launch_bounds__(256, 4) void attn_kernel(
    const __bf16* __restrict__ qhb, const __bf16* __restrict__ kpk,
    const __bf16* __restrict__ vpk, const float* __restrict__ Wrk,
    const float* __restrict__ rwb, const float* __restrict__ rrb,
    __bf16* __restrict__ P) {
    __shared__ float SsL[32][35];
    __shared__ unsigned char dtab[4096];
    __shared__ float mlbuf[4][32][2];
    __shared__ float linv[32];
    __shared__ float obufA[32][97];
    __shared__ float obufB[32][97];
    const int tid = threadIdx.x;
    const int w = tid >> 6, lane = tid & 63;
    const int q = lane & 31, hi = lane >> 5;
    const int n = blockIdx.x;
    const int xcd = n & 7, slot = n >> 3;
    const int bh = xcd + 8 * (slot >> 6);
    const int t0 = (slot & 63) * 32;
    const int b = bh >> 3, h = bh & 7;

    // ---- Q fragments (content bias already folded in) ----
    const __bf16* qrow = qhb + ((size_t)bh * Tn + t0 + q) * Kn + hi * 8;
    bf16x8 qf[4];
#pragma unroll
    for (int kt = 0; kt < 4; ++kt) qf[kt] = *(const bf16x8*)(qrow + kt * 16);

    // ---- dtab ----
    for (int idx = tid; idx < 4095; idx += 256) {
        const int d = idx - 2047;
        const int a = d < 0 ? -d : d;
        const int fi = (int)(__log2f((float)(a + 1)) * F0_SCALE);
        const int col = d > 0 ? fi : (d < 0 ? 17 + fi : 34);
        dtab[idx] = (unsigned char)(col * 4);
    }

    // ---- stage Wrk h-slice into obufB scratch ----
    float* wlds = &obufB[0][0];
    for (int idx = tid; idx < 512; idx += 256) {
        const int i = idx >> 4, jj = (idx & 15) * 4;
        *(float4*)&wlds[i * 64 + jj] = *(const float4*)&Wrk[(size_t)i * (Hn * Kn) + h * Kn + jj];
    }
    __syncthreads();

    // ---- us[q][i] = sum_k (qf + (rrb-rwb))[k] * Wrk[i][k] ----
    {
        float val[32];
#pragma unroll
        for (int kt = 0; kt < 4; ++kt) {
            const int kb = kt * 16 + hi * 8;
            const float4 ra = *(const float4*)&rrb[h * Kn + kb];
            const float4 rb = *(const float4*)&rrb[h * Kn + kb + 4];
            const float4 wa = *(const float4*)&rwb[h * Kn + kb];
            const float4 wb = *(const float4*)&rwb[h * Kn + kb + 4];
            val[kt * 8 + 0] = (float)qf[kt][0] + (ra.x - wa.x);
            val[kt * 8 + 1] = (float)qf[kt][1] + (ra.y - wa.y);
            val[kt * 8 + 2] = (float)qf[kt][2] + (ra.z - wa.z);
            val[kt * 8 + 3] = (float)qf[kt][3] + (ra.w - wa.w);
            val[kt * 8 + 4] = (float)qf[kt][4] + (rb.x - wb.x);
            val[kt * 8 + 5] = (float)qf[kt][5] + (rb.y - wb.y);
            val[kt * 8 + 6] = (float)qf[kt][6] + (rb.z - wb.z);
            val[kt * 8 + 7] = (float)qf[kt][7] + (rb.w - wb.w);
        }
#pragma unroll
        for (int il = 0; il < 8; ++il) {
            const int i = w * 8 + il;
            float partial = 0.f;
#pragma unroll
            for (int kt = 0; kt < 4; ++kt) {
                const int kb = kt * 16 + hi * 8;
                const float4 w0 = *(const float4*)&wlds[i * 64 + kb];
                const float4 w1 = *(const float4*)&wlds[i * 64 + kb + 4];
                partial += val[kt * 8 + 0] * w0.x + val[kt * 8 + 1] * w0.y +
                           val[kt * 8 + 2] * w0.z + val[kt * 8 + 3] * w0.w +
                           val[kt * 8 + 4] * w1.x + val[kt * 8 + 5] * w1.y +
                           val[kt * 8 + 6] * w1.z + val[kt * 8 + 7] * w1.w;
            }
            partial += __shfl_xor(partial, 32);
            if (hi == 0) obufA[q][i] = partial;
        }
    }
    __syncthreads();
    // ---- suffix sums -> SsL ----
    if (tid < 32) {
        const int row = tid;
        float* dst = SsL[row];
        float s1 = 0.f, s2 = 0.f;
        dst[16] = 0.f; dst[33] = 0.f;
        for (int i = 15; i >= 0; --i) {
            s1 += obufA[row][i]; s2 += obufA[row][16 + i];
            dst[i] = (s1 + s2) * LOG2E;        // d > 0
            dst[17 + i] = (s1 - s2) * LOG2E;   // d < 0
        }
        dst[34] = s1 * LOG2E;                  // d == 0
    }

    f32x16 acc0 = {0.f}, acc1 = {0.f}, acc2 = {0.f};
    float m = -3.0e38f, l = 0.f;

    const size_t kp0 = (size_t)(bh * 64) * 4 * 512 + lane * 8;
    const size_t vp0 = (size_t)(bh * 64) * 6 * 512 + lane * 8;
    const int sBeg = w * (Tn / 4);
    const char* sslrow = (const char*)(&SsL[q][0]);

    __syncthreads();   // SsL + dtab ready

    for (int itile = 0; itile < Tn / 4 / 32; ++itile) {
        const int s0 = sBeg + itile * 32;
        const int tIdx = s0 >> 5;
        // ---- QK^T: 4 coalesced K-fragment loads ----
        const __bf16* kr = kpk + kp0 + (size_t)tIdx * (4 * 512);
        f32x16 st = {0.f};
#pragma unroll
        for (int kt = 0; kt < 4; ++kt) {
            const bf16x8 kf = *(const bf16x8*)(kr + kt * 512);
            st = __builtin_amdgcn_mfma_f32_32x32x16_bf16(kf, qf[kt], st, 0, 0, 0);
        }
        // ---- rel bias via LDS tables + online softmax (base-2) ----
        const unsigned char* dp = dtab + (s0 - t0 - q + 2047);
        float p[16];
        float mt = -3.0e38f;
#pragma unroll
        for (int r = 0; r < 16; ++r) {
            const int kr2 = (r & 3) + 8 * (r >> 2) + 4 * hi;
            const int off = dp[kr2];
            const float bias = *(const float*)(sslrow + off);
            p[r] = st[r] + bias;
            mt = fmaxf(mt, p[r]);
        }
        if (!__all(mt - m <= 8.0f)) {
            mt = fmaxf(mt, __shfl_xor(mt, 32));
            const float mn = fmaxf(m, mt);
            const float sc = EXP2F(m - mn);
            m = mn;
            l *= sc;
            acc0 *= sc; acc1 *= sc; acc2 *= sc;
        }
        float ssum = 0.f;
#pragma unroll
        for (int r = 0; r < 16; ++r) { p[r] = EXP2F(p[r] - m); ssum += p[r]; }
        ssum += __shfl_xor(ssum, 32);
        l += ssum;
        // ---- pack P to bf16 B-fragments ----
        unsigned int c[8];
#pragma unroll
        for (int i = 0; i < 8; ++i) {
            union { __bf16 hh[2]; unsigned int u; } uu;
            uu.hh[0] = (__bf16)p[2 * i]; uu.hh[1] = (__bf16)p[2 * i + 1];
            c[i] = uu.u;
        }
        union { unsigned int u[4]; bf16x8 v; } B0, B1;
#if __has_builtin(__builtin_amdgcn_permlane32_swap)
        {
            auto r0 = __builtin_amdgcn_permlane32_swap((int)c[0], (int)c[2], false, false);
            auto r1 = __builtin_amdgcn_permlane32_swap((int)c[1], (int)c[3], false, false);
            auto r2 = __builtin_amdgcn_permlane32_swap((int)c[4], (int)c[6], false, false);
            auto r3 = __builtin_amdgcn_permlane32_swap((int)c[5], (int)c[7], false, false);
            B0.u[0] = (unsigned int)r0[0]; B0.u[2] = (unsigned int)r0[1];
            B0.u[1] = (unsigned int)r1[0]; B0.u[3] = (unsigned int)r1[1];
            B1.u[0] = (unsigned int)r2[0]; B1.u[2] = (unsigned int)r2[1];
            B1.u[1] = (unsigned int)r3[0]; B1.u[3] = (unsigned int)r3[1];
        }
#else
        {
            unsigned int x[8];
#pragma unroll
            for (int i = 0; i < 8; ++i) x[i] = __shfl_xor(c[i], 32);
            B0.u[0] = hi ? x[2] : c[0]; B0.u[1] = hi ? x[3] : c[1];
            B0.u[2] = hi ? c[2] : x[0]; B0.u[3] = hi ? c[3] : x[1];
            B1.u[0] = hi ? x[6] : c[4]; B1.u[1] = hi ? x[7] : c[5];
            B1.u[2] = hi ? c[6] : x[4]; B1.u[3] = hi ? c[7] : x[5];
        }
#endif
        // ---- PV: 6 coalesced V-fragment loads (at point of use) ----
        const __bf16* vr = vpk + vp0 + (size_t)tIdx * (6 * 512);
        acc0 = __builtin_amdgcn_mfma_f32_32x32x16_bf16(*(const bf16x8*)(vr + 0 * 512), B0.v, acc0, 0, 0, 0);
        acc0 = __builtin_amdgcn_mfma_f32_32x32x16_bf16(*(const bf16x8*)(vr + 1 * 512), B1.v, acc0, 0, 0, 0);
        acc1 = __builtin_amdgcn_mfma_f32_32x32x16_bf16(*(const bf16x8*)(vr + 2 * 512), B0.v, acc1, 0, 0, 0);
        acc1 = __builtin_amdgcn_mfma_f32_32x32x16_bf16(*(const bf16x8*)(vr + 3 * 512), B1.v, acc1, 0, 0, 0);
        acc2 = __builtin_amdgcn_mfma_f32_32x32x16_bf16(*(const bf16x8*)(vr + 4 * 512), B0.v, acc2, 0, 0, 0);
        acc2 = __builtin_amdgcn_mfma_f32_32x32x16_bf16(*(const bf16x8*)(vr + 5 * 512), B1.v, acc2, 0, 0, 0);
    }

    // ---- flash combine across the 4 waves (base-2 weights) ----
    if (lane < 32) { mlbuf[w][q][0] = m; mlbuf[w][q][1] = l; }
    __syncthreads();
    const float mstar = fmaxf(fmaxf(mlbuf[0][q][0], mlbuf[1][q][0]),
                              fmaxf(mlbuf[2][q][0], mlbuf[3][q][0]));
    const float wme = EXP2F(m - mstar);
    if (w == 0 && lane < 32) {
        float ls = 0.f;
#pragma unroll
        for (int ww = 0; ww < 4; ++ww)
            ls += mlbuf[ww][q][1] * EXP2F(mlbuf[ww][q][0] - mstar);
        linv[q] = 1.f / ls;
    }
    float (*bufp)[97] = (w & 1) ? obufB : obufA;
    if (w < 2) {
#pragma unroll
        for (int r = 0; r < 16; ++r) {
            const int vr2 = (r & 3) + 8 * (r >> 2) + 4 * hi;
            bufp[q][vr2] = acc0[r] * wme;
            bufp[q][32 + vr2] = acc1[r] * wme;
            bufp[q][64 + vr2] = acc2[r] * wme;
        }
    }
    __syncthreads();
    if (w >= 2) {
#pragma unroll
        for (int r = 0; r < 16; ++r) {
            const int vr2 = (r & 3) + 8 * (r >> 2) + 4 * hi;
            bufp[q][vr2] += acc0[r] * wme;
            bufp[q][32 + vr2] += acc1[r] * wme;
            bufp[q][64 + vr2] += acc2[r] * wme;
        }
    }
    __syncthreads();
    const int qo = tid >> 3, v0 = (tid & 7) * 12;
    const float li = linv[qo];
    __bf16* prow = P + ((size_t)b * Tn + t0 + qo) * Dn + h * Vn + v0;
#pragma unroll
    for (int j = 0; j < 12; j += 2) {
        const float u0 = (obufA[qo][v0 + j] + obufB[qo][v0 + j]) * li;
        const float u1 = (obufA[qo][v0 + j + 1] + obufB[qo][v0 + j + 1]) * li;
        union { __bf16 hh[2]; unsigned int u; } pk;
        pk.hh[0] = (__bf16)u0; pk.hh[1] = (__bf16)u1;
        *(unsigned int*)(prow + j) = pk.u;
    }
}

extern "C" void kernel_launch(void* const* d_in, const int* in_sizes, int n_in,
                              void* d_out, int out_size, void* d_ws, size_t ws_size,
                              hipStream_t stream) {
    (void)in_sizes; (void)n_in; (void)out_size; (void)ws_size;
    const float* x   = (const float*)d_in[0];
    const float* Wq  = (const float*)d_in[1];
    const float* Wk  = (const float*)d_in[2];
    const float* Wv  = (const float*)d_in[3];
    const float* Wrk = (const float*)d_in[4];
    const float* rwb = (const float*)d_in[5];
    const float* rrb = (const float*)d_in[6];
    const float* Wo  = (const float*)d_in[7];
    const float* bo  = (const float*)d_in[8];
    float* out = (float*)d_out;

    char* p = (char*)d_ws;
    auto alloc = [&](size_t bytes) { char* r = p; p += (bytes + 255) & ~(size_t)255; return r; };
    __bf16* qhb  = (__bf16*)alloc((size_t)Bn * Hn * Tn * Kn * 2);
    __bf16* kpk  = (__bf16*)alloc((size_t)Bn * Hn * 64 * 4 * 512 * 2);
    __bf16* vpk  = (__bf16*)alloc((size_t)Bn * Hn * 64 * 6 * 512 * 2);
    __bf16* Pmb  = (__bf16*)alloc((size_t)Bn * Tn * Dn * 2);
    __bf16* Xb   = (__bf16*)alloc((size_t)Bn * Tn * Dn * 2);
    __bf16* WT   = (__bf16*)alloc((size_t)1792 * 768 * 2);
    __bf16* WoT  = (__bf16*)alloc((size_t)768 * 768 * 2);

    transpose5_kernel<<<dim3(24, 24, 5), 256, 0, stream>>>(Wq, Wk, Wv, Wo, x, WT, WoT, Xb);
    gemm_kernel<<<dim3(14, 32), 256, 0, stream>>>(Xb, WT, 768, 0, qhb, kpk, vpk, nullptr, rwb);
    attn_kernel<<<dim3(1024), 256, 0, stream>>>(qhb, kpk, vpk, Wrk, rwb, rrb, Pmb);
    gemm_kernel<<<dim3(6, 32), 256, 0, stream>>>(Pmb, WoT, 768, 1, nullptr, nullptr, nullptr, out, bo);
}